// Round 4
// baseline (286.389 us; speedup 1.0000x reference)
//
#include <hip/hip_runtime.h>
#include <hip/hip_bf16.h>
#include <math.h>

typedef __bf16 bf16;
typedef __bf16 bf16x8 __attribute__((ext_vector_type(8)));
typedef float  f32x4  __attribute__((ext_vector_type(4)));

#define MFMA16(a,b,c) __builtin_amdgcn_mfma_f32_16x16x32_bf16((a),(b),(c),0,0,0)
#define ATT_SCALE 0.0441941738241592f  /* 1/sqrt(512) */

// async global->LDS, 16 B/lane; LDS dest = wave-uniform base + lane*16
__device__ __forceinline__ void async16p(const void* g, void* l) {
    __builtin_amdgcn_global_load_lds((const __attribute__((address_space(1))) void*)g,
                                     (__attribute__((address_space(3))) void*)l,
                                     16, 0, 0);
}

// ---------------- prep: transpose 4 weights fp32[k][n] -> bf16 T[n][k] -----
__global__ __launch_bounds__(256) void prep_w_kernel(
    const float* __restrict__ Wq, const float* __restrict__ Wk,
    const float* __restrict__ Wv, const float* __restrict__ Wo,
    bf16* __restrict__ WqT, bf16* __restrict__ WkT,
    bf16* __restrict__ WvT, bf16* __restrict__ WoT)
{
    __shared__ float tile[32][33];
    const int bx = blockIdx.x;
    const float* W; bf16* T;
    switch (bx >> 8) {
      case 0: W=Wq; T=WqT; break;
      case 1: W=Wk; T=WkT; break;
      case 2: W=Wv; T=WvT; break;
      default: W=Wo; T=WoT; break;
    }
    const int rest = bx & 255;
    const int k0 = (rest & 15) * 32, n0 = (rest >> 4) * 32;
    const int tx = threadIdx.x & 31, ty = threadIdx.x >> 5;
    #pragma unroll
    for (int i=0;i<32;i+=8)
        tile[ty+i][tx] = W[(size_t)(k0+ty+i)*512 + n0+tx];
    __syncthreads();
    #pragma unroll
    for (int i=0;i<32;i+=8)
        T[(size_t)(n0+ty+i)*512 + k0+tx] = (bf16)tile[tx][ty+i];
}

// ------------- projection GEMM: fp32 A staged async, bf16 weights ----------
// z=0: q = Q@Wq+bq -> qbb.  z=1: k = K@Wk+bk -> kbb AND v = K@Wv+bv -> vT.
// A tile 128x32 fp32 (XOR-swizzled granules), B tiles 128x32 bf16 (swizzled).
__global__ __launch_bounds__(256, 2) void gemm_qkv_kernel(
    const float* __restrict__ Qf, const float* __restrict__ Kf,
    const bf16* __restrict__ WqT, const bf16* __restrict__ WkT,
    const bf16* __restrict__ WvT,
    const float* __restrict__ bq, const float* __restrict__ bk,
    const float* __restrict__ bv,
    bf16* __restrict__ qbb, bf16* __restrict__ kbb, bf16* __restrict__ vT)
{
    __shared__ float As32[128*32];
    __shared__ bf16  Bs0[128*32];
    __shared__ bf16  Bs1[128*32];
    __shared__ bf16  Lt[64][136];
    const bool kv = (blockIdx.z != 0);
    const float* A   = kv ? Kf : Qf;
    const bf16*  BT0 = kv ? WkT : WqT;
    const float* b0  = kv ? bk : bq;
    bf16* C0 = kv ? kbb : qbb;

    const int m0 = blockIdx.x * 128, n0 = blockIdx.y * 128;
    const int tid = threadIdx.x;
    const int lane = tid & 63, wave = tid >> 6;
    const int qd = lane >> 4, lr = lane & 15;
    const int wm = (wave & 1) * 64, wn = (wave >> 1) * 64;

    // A staging: row tid>>3, granule (tid&7)^((tid>>3)&7) of 4 floats
    const float* gA = A + (size_t)(m0 + (tid>>3))*512 + (((tid&7)^((tid>>3)&7))*4);
    float* lA = As32 + wave*256;
    // B staging: row tid>>2, granule (tid&3)^((tid>>2)&3) of 8 bf16
    const int bgr = ((tid&3)^((tid>>2)&3))*8;
    const bf16* gB0 = BT0 + (size_t)(n0 + (tid>>2))*512 + bgr;
    const bf16* gB1 = WvT + (size_t)(n0 + (tid>>2))*512 + bgr;
    bf16* lB0 = Bs0 + wave*512;
    bf16* lB1 = Bs1 + wave*512;

    f32x4 acc0[4][4], acc1[4][4];
    #pragma unroll
    for (int i=0;i<4;i++)
      #pragma unroll
      for (int j=0;j<4;j++) { acc0[i][j] = (f32x4){0,0,0,0}; acc1[i][j] = (f32x4){0,0,0,0}; }

    for (int k0 = 0; k0 < 512; k0 += 32) {
        __syncthreads();
        #pragma unroll
        for (int i=0;i<4;i++)
            async16p(gA + k0 + (size_t)i*32*512, lA + i*1024);
        async16p(gB0 + k0,            lB0);
        async16p(gB0 + k0 + 64*512,   lB0 + 2048);
        if (kv) {
            async16p(gB1 + k0,          lB1);
            async16p(gB1 + k0 + 64*512, lB1 + 2048);
        }
        __syncthreads();
        bf16x8 af[4], bf0[4], bf1[4];
        #pragma unroll
        for (int mi=0;mi<4;mi++) {
            int row = wm + mi*16 + lr;
            f32x4 f0 = *(f32x4*)(As32 + row*32 + (((qd*2  )^(lr&7))*4));
            f32x4 f1 = *(f32x4*)(As32 + row*32 + (((qd*2+1)^(lr&7))*4));
            bf16x8 a;
            a[0]=(bf16)f0[0]; a[1]=(bf16)f0[1]; a[2]=(bf16)f0[2]; a[3]=(bf16)f0[3];
            a[4]=(bf16)f1[0]; a[5]=(bf16)f1[1]; a[6]=(bf16)f1[2]; a[7]=(bf16)f1[3];
            af[mi] = a;
        }
        #pragma unroll
        for (int ni=0;ni<4;ni++) {
            int row = wn + ni*16 + lr;
            bf0[ni] = *(bf16x8*)(Bs0 + row*32 + ((qd^(lr&3))*8));
            if (kv) bf1[ni] = *(bf16x8*)(Bs1 + row*32 + ((qd^(lr&3))*8));
        }
        #pragma unroll
        for (int mi=0;mi<4;mi++)
          #pragma unroll
          for (int ni=0;ni<4;ni++) {
            acc0[mi][ni] = MFMA16(af[mi], bf0[ni], acc0[mi][ni]);
            if (kv) acc1[mi][ni] = MFMA16(af[mi], bf1[ni], acc1[mi][ni]);
          }
    }

    // epilogue: C0 (q or k) direct bf16 write
    #pragma unroll
    for (int ni=0;ni<4;ni++) {
        int n = n0 + wn + ni*16 + lr;
        float bv0 = b0[n];
        #pragma unroll
        for (int mi=0;mi<4;mi++) {
            int mb = m0 + wm + mi*16 + qd*4;
            #pragma unroll
            for (int r=0;r<4;r++)
                C0[(size_t)(mb+r)*512 + n] = (bf16)(acc0[mi][ni][r] + bv0);
        }
    }
    if (kv) {   // v -> vT[b][h][d][tok] via LDS transpose, fully coalesced
        const int b = m0 >> 10, tok0 = m0 & 1023;
        const int row = tid >> 2, ch = tid & 3;   // ch covers 32 tokens
        #pragma unroll
        for (int half = 0; half < 2; ++half) {
            __syncthreads();
            if ((wn >> 6) == half) {
                #pragma unroll
                for (int ni=0;ni<4;ni++) {
                    int nl = ni*16 + lr;
                    float bvv = bv[n0 + half*64 + nl];
                    #pragma unroll
                    for (int mi=0;mi<4;mi++)
                      #pragma unroll
                      for (int r=0;r<4;r++)
                        Lt[nl][wm + mi*16 + qd*4 + r] = (bf16)(acc1[mi][ni][r] + bvv);
                }
            }
            __syncthreads();
            const int h = (n0 >> 6) + half;
            bf16* dst = vT + ((size_t)((b*8 + h)*64 + row))*1024 + tok0 + ch*32;
            uint4 x0 = *(uint4*)(&Lt[row][ch*32]);
            uint4 x1 = *(uint4*)(&Lt[row][ch*32 + 8]);
            uint4 x2 = *(uint4*)(&Lt[row][ch*32 + 16]);
            uint4 x3 = *(uint4*)(&Lt[row][ch*32 + 24]);
            *(uint4*)(dst)      = x0;
            *(uint4*)(dst + 8)  = x1;
            *(uint4*)(dst + 16) = x2;
            *(uint4*)(dst + 24) = x3;
        }
    }
}

// ---------------- attention: flash loop, async K/V staging ----------------
// Block = 64 q rows (4 waves x 16). K/V tiles 64x64 bf16 unpadded, XOR-swizzled,
// staged via global_load_lds. grid (16, 8, 16) = 2048 blocks.
__global__ __launch_bounds__(256, 4) void attn_kernel(
    const bf16* __restrict__ qb, const bf16* __restrict__ kb,
    const bf16* __restrict__ vT, bf16* __restrict__ attnb)
{
    const int qt = blockIdx.x, h = blockIdx.y, b = blockIdx.z;
    const int tid = threadIdx.x, lane = tid & 63, wave = tid >> 6;
    const int qd = lane >> 4, lr = lane & 15;
    const int q0 = qt*64 + wave*16;

    __shared__ bf16 Ks[64*64];
    __shared__ bf16 Vs[64*64];
    __shared__ bf16 Pl[4][16][72];

    bf16x8 aq0, aq1;
    {
        const bf16* qrow = qb + ((size_t)(b*1024 + q0 + lr))*512 + h*64;
        aq0 = *(const bf16x8*)(qrow + qd*8);
        aq1 = *(const bf16x8*)(qrow + 32 + qd*8);
    }

    // staging source (lane l): row w*8+(l>>3) [+j*32], granule (l&7)^((l>>3)&7)
    const int srow = (tid >> 3) & 7;            // l>>3 within wave
    const int sgr  = ((tid&7) ^ srow) * 8;
    const bf16* kgp = kb + ((size_t)(b*1024 + wave*8 + srow))*512 + h*64 + sgr;
    const bf16* vgp = vT + ((size_t)((b*8 + h)*64 + wave*8 + srow))*1024 + sgr;
    bf16* lK = Ks + wave*512;
    bf16* lV = Vs + wave*512;

    f32x4 acc[4];
    #pragma unroll
    for (int i=0;i<4;i++) acc[i] = (f32x4){0,0,0,0};
    float l[4] = {0.f,0.f,0.f,0.f};

    for (int t=0; t<16; ++t) {
        const int kk0 = t*64;
        __syncthreads();
        async16p(kgp + (size_t)kk0*512,            lK);
        async16p(kgp + (size_t)(kk0+32)*512,       lK + 2048);
        async16p(vgp + kk0,                        lV);
        async16p(vgp + (size_t)32*1024 + kk0,      lV + 2048);
        __syncthreads();

        f32x4 s[4];
        #pragma unroll
        for (int ni=0;ni<4;ni++) s[ni] = (f32x4){0,0,0,0};
        #pragma unroll
        for (int ni=0;ni<4;ni++) {
            int row = ni*16 + lr;
            bf16x8 b0 = *(bf16x8*)(Ks + row*64 + (((qd  )^(lr&7))*8));
            bf16x8 b1 = *(bf16x8*)(Ks + row*64 + (((qd+4)^(lr&7))*8));
            s[ni] = MFMA16(aq0, b0, s[ni]);
            s[ni] = MFMA16(aq1, b1, s[ni]);
        }
        #pragma unroll
        for (int ni=0;ni<4;ni++)
          #pragma unroll
          for (int r=0;r<4;r++) {
            float pv = __expf(s[ni][r] * ATT_SCALE);
            s[ni][r] = pv;
            l[r] += pv;
          }
        #pragma unroll
        for (int ni=0;ni<4;ni++)
          #pragma unroll
          for (int r=0;r<4;r++)
            Pl[wave][qd*4+r][ni*16+lr] = (bf16)s[ni][r];
        bf16x8 ap0 = *(bf16x8*)(&Pl[wave][lr][qd*8]);
        bf16x8 ap1 = *(bf16x8*)(&Pl[wave][lr][32+qd*8]);
        #pragma unroll
        for (int ni=0;ni<4;ni++) {
            int row = ni*16 + lr;
            bf16x8 v0 = *(bf16x8*)(Vs + row*64 + (((qd  )^(lr&7))*8));
            bf16x8 v1 = *(bf16x8*)(Vs + row*64 + (((qd+4)^(lr&7))*8));
            acc[ni] = MFMA16(ap0, v0, acc[ni]);
            acc[ni] = MFMA16(ap1, v1, acc[ni]);
        }
    }

    #pragma unroll
    for (int off=1; off<16; off<<=1)
      #pragma unroll
      for (int r=0;r<4;r++) l[r] += __shfl_xor(l[r], off);

    float inv[4];
    #pragma unroll
    for (int r=0;r<4;r++) inv[r] = 1.f / l[r];
    #pragma unroll
    for (int ni=0;ni<4;ni++)
      #pragma unroll
      for (int r=0;r<4;r++)
        Pl[wave][qd*4+r][ni*16+lr] = (bf16)(acc[ni][r] * inv[r]);
    bf16x8 oA = *(bf16x8*)(&Pl[wave][lr][qd*8]);
    bf16x8 oB = *(bf16x8*)(&Pl[wave][lr][32+qd*8]);
    bf16* dst = attnb + ((size_t)(b*1024 + q0 + lr))*512 + h*64;
    *(bf16x8*)(dst + qd*8)      = oA;
    *(bf16x8*)(dst + 32 + qd*8) = oB;
}

// ---------------- ln0: O = LN(q + attn); write bf16 Obf + fp32 O32 --------
__global__ __launch_bounds__(256) void ln0_kernel(
    const bf16* __restrict__ qbb, const bf16* __restrict__ attnb,
    bf16* __restrict__ Obf, float* __restrict__ O32)
{
    const int wave = threadIdx.x >> 6, lane = threadIdx.x & 63;
    const int row = blockIdx.x*4 + wave;
    const size_t base = (size_t)row*512 + lane*8;
    bf16x8 qv = *(const bf16x8*)(qbb + base);
    bf16x8 av = *(const bf16x8*)(attnb + base);
    float x[8];
    #pragma unroll
    for (int i=0;i<8;i++) x[i] = (float)qv[i] + (float)av[i];
    float s1 = 0.f, s2 = 0.f;
    #pragma unroll
    for (int i=0;i<8;i++){ s1 += x[i]; s2 += x[i]*x[i]; }
    #pragma unroll
    for (int off=1; off<64; off<<=1) { s1 += __shfl_xor(s1, off); s2 += __shfl_xor(s2, off); }
    float mu  = s1 * (1.f/512.f);
    float var = s2 * (1.f/512.f) - mu*mu;
    float rstd = rsqrtf(var + 1e-5f);
    bf16x8 ob; float4 o0, o1;
    float y[8];
    #pragma unroll
    for (int i=0;i<8;i++) { y[i] = (x[i]-mu)*rstd; ob[i] = (bf16)y[i]; }
    o0 = (float4){y[0],y[1],y[2],y[3]};
    o1 = (float4){y[4],y[5],y[6],y[7]};
    *(bf16x8*)(Obf + base) = ob;
    *(float4*)(O32 + base)     = o0;
    *(float4*)(O32 + base + 4) = o1;
}

// ------- gemm_o: G = Obf@WoT + bo; x32 = O32 + gelu(G)  (fused epilogue) ---
__global__ __launch_bounds__(256, 3) void gemm_o_kernel(
    const bf16* __restrict__ Obf, const bf16* __restrict__ WoT,
    const float* __restrict__ bo, const float* __restrict__ O32,
    float* __restrict__ x32)
{
    __shared__ bf16 As[128*32];
    __shared__ bf16 Bs[128*32];
    const int m0 = blockIdx.x * 128, n0 = blockIdx.y * 128;
    const int tid = threadIdx.x;
    const int lane = tid & 63, wave = tid >> 6;
    const int qd = lane >> 4, lr = lane & 15;
    const int wm = (wave & 1) * 64, wn = (wave >> 1) * 64;

    const int gr = ((tid&3)^((tid>>2)&3))*8;
    const bf16* gA = Obf + (size_t)(m0 + (tid>>2))*512 + gr;
    const bf16* gB = WoT + (size_t)(n0 + (tid>>2))*512 + gr;
    bf16* lA = As + wave*512;
    bf16* lB = Bs + wave*512;

    f32x4 acc[4][4];
    #pragma unroll
    for (int i=0;i<4;i++)
      #pragma unroll
      for (int j=0;j<4;j++) acc[i][j] = (f32x4){0,0,0,0};

    for (int k0 = 0; k0 < 512; k0 += 32) {
        __syncthreads();
        async16p(gA + k0,          lA);
        async16p(gA + k0 + 64*512, lA + 2048);
        async16p(gB + k0,          lB);
        async16p(gB + k0 + 64*512, lB + 2048);
        __syncthreads();
        bf16x8 af[4], bfr[4];
        #pragma unroll
        for (int mi=0;mi<4;mi++) af[mi]  = *(bf16x8*)(As + (wm+mi*16+lr)*32 + ((qd^(lr&3))*8));
        #pragma unroll
        for (int ni=0;ni<4;ni++) bfr[ni] = *(bf16x8*)(Bs + (wn+ni*16+lr)*32 + ((qd^(lr&3))*8));
        #pragma unroll
        for (int mi=0;mi<4;mi++)
          #pragma unroll
          for (int ni=0;ni<4;ni++)
            acc[mi][ni] = MFMA16(af[mi], bfr[ni], acc[mi][ni]);
    }

    #pragma unroll
    for (int ni=0;ni<4;ni++) {
        int n = n0 + wn + ni*16 + lr;
        float bv = bo[n];
        #pragma unroll
        for (int mi=0;mi<4;mi++) {
            int mb = m0 + wm + mi*16 + qd*4;
            #pragma unroll
            for (int r=0;r<4;r++) {
                float g = acc[mi][ni][r] + bv;
                float gelu = 0.5f * g * (1.f + erff(g * 0.70710678118654752f));
                size_t idx = (size_t)(mb+r)*512 + n;
                x32[idx] = O32[idx] + gelu;
            }
        }
    }
}

// ---------------- ln1: out = LN(x32) ----------------
__global__ __launch_bounds__(256) void ln1_kernel(
    const float* __restrict__ x32, float* __restrict__ out)
{
    const int wave = threadIdx.x >> 6, lane = threadIdx.x & 63;
    const int row = blockIdx.x*4 + wave;
    const size_t base = (size_t)row*512 + lane*8;
    float4 a0 = *(const float4*)(x32 + base);
    float4 a1 = *(const float4*)(x32 + base + 4);
    float x[8] = {a0.x,a0.y,a0.z,a0.w,a1.x,a1.y,a1.z,a1.w};
    float s1 = 0.f, s2 = 0.f;
    #pragma unroll
    for (int i=0;i<8;i++){ s1 += x[i]; s2 += x[i]*x[i]; }
    #pragma unroll
    for (int off=1; off<64; off<<=1) { s1 += __shfl_xor(s1, off); s2 += __shfl_xor(s2, off); }
    float mu  = s1 * (1.f/512.f);
    float var = s2 * (1.f/512.f) - mu*mu;
    float rstd = rsqrtf(var + 1e-5f);
    float4 o0 = {(x[0]-mu)*rstd,(x[1]-mu)*rstd,(x[2]-mu)*rstd,(x[3]-mu)*rstd};
    float4 o1 = {(x[4]-mu)*rstd,(x[5]-mu)*rstd,(x[6]-mu)*rstd,(x[7]-mu)*rstd};
    *(float4*)(out + base)     = o0;
    *(float4*)(out + base + 4) = o1;
}

extern "C" void kernel_launch(void* const* d_in, const int* in_sizes, int n_in,
                              void* d_out, int out_size, void* d_ws, size_t ws_size,
                              hipStream_t stream)
{
    (void)in_sizes; (void)n_in; (void)out_size; (void)ws_size;
    const float* Q  = (const float*)d_in[0];
    const float* K  = (const float*)d_in[1];
    const float* Wq = (const float*)d_in[2];
    const float* bq = (const float*)d_in[3];
    const float* Wk = (const float*)d_in[4];
    const float* bk = (const float*)d_in[5];
    const float* Wv = (const float*)d_in[6];
    const float* bv = (const float*)d_in[7];
    const float* Wo = (const float*)d_in[8];
    const float* bo = (const float*)d_in[9];
    float* out = (float*)d_out;

    const size_t nTok = (size_t)16*1024*512;   // 8.39M elements
    char* p = (char*)d_ws;
    auto alloc = [&](size_t bytes)->char* {
        char* r = p; p += (bytes + 255) & ~(size_t)255; return r;
    };
    bf16* WqT   = (bf16*)alloc(512*512*2);
    bf16* WkT   = (bf16*)alloc(512*512*2);
    bf16* WvT   = (bf16*)alloc(512*512*2);
    bf16* WoT   = (bf16*)alloc(512*512*2);
    bf16* qbb   = (bf16*)alloc(nTok*2);
    bf16* kbb   = (bf16*)alloc(nTok*2);
    bf16* vT    = (bf16*)alloc(nTok*2);
    bf16* attnb = (bf16*)alloc(nTok*2);
    bf16* Obf   = (bf16*)alloc(nTok*2);
    float* O32  = (float*)alloc(nTok*4);
    float* x32  = (float*)alloc(nTok*4);

    prep_w_kernel<<<1024, 256, 0, stream>>>(Wq, Wk, Wv, Wo, WqT, WkT, WvT, WoT);
    gemm_qkv_kernel<<<dim3(128,4,2), 256, 0, stream>>>(Q, K, WqT, WkT, WvT,
                                                       bq, bk, bv, qbb, kbb, vT);
    attn_kernel<<<dim3(16,8,16), 256, 0, stream>>>(qbb, kbb, vT, attnb);
    ln0_kernel<<<4096, 256, 0, stream>>>(qbb, attnb, Obf, O32);
    gemm_o_kernel<<<dim3(128,4), 256, 0, stream>>>(Obf, WoT, bo, O32, x32);
    ln1_kernel<<<4096, 256, 0, stream>>>(x32, out);
}

// Round 5
// 283.805 us; speedup vs baseline: 1.0091x; 1.0091x over previous
//
#include <hip/hip_runtime.h>
#include <hip/hip_bf16.h>
#include <math.h>

typedef __bf16 bf16;
typedef __bf16 bf16x8 __attribute__((ext_vector_type(8)));
typedef float  f32x4  __attribute__((ext_vector_type(4)));

#define MFMA16(a,b,c) __builtin_amdgcn_mfma_f32_16x16x32_bf16((a),(b),(c),0,0,0)
#define ATT_SCALE 0.0441941738241592f  /* 1/sqrt(512) */

// async global->LDS, 16 B/lane; LDS dest = wave-uniform base + lane*16
__device__ __forceinline__ void async16p(const void* g, void* l) {
    __builtin_amdgcn_global_load_lds((const __attribute__((address_space(1))) void*)g,
                                     (__attribute__((address_space(3))) void*)l,
                                     16, 0, 0);
}

// ---------------- prep: transpose 4 weights fp32[k][n] -> bf16 T[n][k] -----
__global__ __launch_bounds__(256) void prep_w_kernel(
    const float* __restrict__ Wq, const float* __restrict__ Wk,
    const float* __restrict__ Wv, const float* __restrict__ Wo,
    bf16* __restrict__ WqT, bf16* __restrict__ WkT,
    bf16* __restrict__ WvT, bf16* __restrict__ WoT)
{
    __shared__ float tile[32][33];
    const int bx = blockIdx.x;
    const float* W; bf16* T;
    switch (bx >> 8) {
      case 0: W=Wq; T=WqT; break;
      case 1: W=Wk; T=WkT; break;
      case 2: W=Wv; T=WvT; break;
      default: W=Wo; T=WoT; break;
    }
    const int rest = bx & 255;
    const int k0 = (rest & 15) * 32, n0 = (rest >> 4) * 32;
    const int tx = threadIdx.x & 31, ty = threadIdx.x >> 5;
    #pragma unroll
    for (int i=0;i<32;i+=8)
        tile[ty+i][tx] = W[(size_t)(k0+ty+i)*512 + n0+tx];
    __syncthreads();
    #pragma unroll
    for (int i=0;i<32;i+=8)
        T[(size_t)(n0+ty+i)*512 + k0+tx] = (bf16)tile[tx][ty+i];
}

// ------------- projection GEMM: fp32 A staged async, bf16 weights ----------
// z=0: q=Q@Wq+bq -> qbb ; z=1: k=K@Wk+bk -> kbb ; z=2: v=K@Wv+bv -> vT.
// Uniform blocks, 128x128 tile, BK=32. Lt transpose tile overlays As32.
__global__ __launch_bounds__(256, 3) void gemm_qkv_kernel(
    const float* __restrict__ Qf, const float* __restrict__ Kf,
    const bf16* __restrict__ WqT, const bf16* __restrict__ WkT,
    const bf16* __restrict__ WvT,
    const float* __restrict__ bq, const float* __restrict__ bk,
    const float* __restrict__ bv,
    bf16* __restrict__ qbb, bf16* __restrict__ kbb, bf16* __restrict__ vT)
{
    __shared__ __align__(16) char smem[32768];
    float* As32 = (float*)smem;            // 128x32 fp32 = 16 KB
    bf16*  Bs   = (bf16*)(smem + 16384);   // 128x32 bf16 = 8 KB
    bf16*  Lt   = (bf16*)smem;             // 64x128 bf16 (overlays As32, epilogue only)

    const int z = blockIdx.z;
    const float* A  = (z == 0) ? Qf : Kf;
    const bf16*  BT = (z == 0) ? WqT : (z == 1) ? WkT : WvT;
    const float* bb = (z == 0) ? bq  : (z == 1) ? bk  : bv;

    const int m0 = blockIdx.x * 128, n0 = blockIdx.y * 128;
    const int tid = threadIdx.x;
    const int lane = tid & 63, wave = tid >> 6;
    const int qd = lane >> 4, lr = lane & 15;
    const int wm = (wave & 1) * 64, wn = (wave >> 1) * 64;

    const float* gA = A + (size_t)(m0 + (tid>>3))*512 + (((tid&7)^((tid>>3)&7))*4);
    float* lA = As32 + wave*256;
    const bf16* gB = BT + (size_t)(n0 + (tid>>2))*512 + (((tid&3)^((tid>>2)&3))*8);
    bf16* lB = Bs + wave*512;

    f32x4 acc[4][4];
    #pragma unroll
    for (int i=0;i<4;i++)
      #pragma unroll
      for (int j=0;j<4;j++) acc[i][j] = (f32x4){0,0,0,0};

    for (int k0 = 0; k0 < 512; k0 += 32) {
        __syncthreads();
        #pragma unroll
        for (int i=0;i<4;i++)
            async16p(gA + k0 + (size_t)i*32*512, lA + i*1024);
        async16p(gB + k0,          lB);
        async16p(gB + k0 + 64*512, lB + 2048);
        __syncthreads();
        bf16x8 af[4], bfr[4];
        #pragma unroll
        for (int mi=0;mi<4;mi++) {
            int row = wm + mi*16 + lr;
            f32x4 f0 = *(f32x4*)(As32 + row*32 + (((qd*2  )^(lr&7))*4));
            f32x4 f1 = *(f32x4*)(As32 + row*32 + (((qd*2+1)^(lr&7))*4));
            bf16x8 a;
            a[0]=(bf16)f0[0]; a[1]=(bf16)f0[1]; a[2]=(bf16)f0[2]; a[3]=(bf16)f0[3];
            a[4]=(bf16)f1[0]; a[5]=(bf16)f1[1]; a[6]=(bf16)f1[2]; a[7]=(bf16)f1[3];
            af[mi] = a;
        }
        #pragma unroll
        for (int ni=0;ni<4;ni++)
            bfr[ni] = *(bf16x8*)(Bs + (wn+ni*16+lr)*32 + ((qd^(lr&3))*8));
        #pragma unroll
        for (int mi=0;mi<4;mi++)
          #pragma unroll
          for (int ni=0;ni<4;ni++)
            acc[mi][ni] = MFMA16(af[mi], bfr[ni], acc[mi][ni]);
    }

    if (z < 2) {   // q or k: direct bf16 row-major write
        bf16* C = (z == 0) ? qbb : kbb;
        #pragma unroll
        for (int ni=0;ni<4;ni++) {
            int n = n0 + wn + ni*16 + lr;
            float bv0 = bb[n];
            #pragma unroll
            for (int mi=0;mi<4;mi++) {
                int mb = m0 + wm + mi*16 + qd*4;
                #pragma unroll
                for (int r=0;r<4;r++)
                    C[(size_t)(mb+r)*512 + n] = (bf16)(acc[mi][ni][r] + bv0);
            }
        }
    } else {       // v: vT[b][h][d][tok] via swizzled LDS transpose (overlays As32)
        const int b = m0 >> 10, tok0 = m0 & 1023;
        const int row = tid >> 2, ch = tid & 3;
        #pragma unroll
        for (int half = 0; half < 2; ++half) {
            __syncthreads();   // all As32 reads done / prev half consumed
            if ((wn >> 6) == half) {
                #pragma unroll
                for (int ni=0;ni<4;ni++) {
                    int nl = ni*16 + lr;
                    float bvv = bb[n0 + half*64 + nl];
                    #pragma unroll
                    for (int mi=0;mi<4;mi++)
                      #pragma unroll
                      for (int r=0;r<4;r++) {
                        int col = wm + mi*16 + qd*4 + r;
                        Lt[nl*128 + ((((col>>3)^(nl&7))<<3) | (col&7))]
                            = (bf16)(acc[mi][ni][r] + bvv);
                      }
                }
            }
            __syncthreads();
            const int h = (n0 >> 6) + half;
            bf16* dst = vT + ((size_t)((b*8 + h)*64 + row))*1024 + tok0 + ch*32;
            #pragma unroll
            for (int s=0;s<4;s++) {
                int g = (ch*4 + s) ^ (row & 7);
                *(uint4*)(dst + s*8) = *(uint4*)(Lt + row*128 + g*8);
            }
        }
    }
}

// ---------------- attention: flash loop, double-buffered async K/V ---------
// Block = 64 q rows (4 waves x 16). K/V tiles 64x64, XOR-swizzled, staged via
// global_load_lds into alternating buffers: loads for tile t+1 issued right
// after the barrier for tile t -> full compute phase in flight before drain.
__global__ __launch_bounds__(256, 3) void attn_kernel(
    const bf16* __restrict__ qb, const bf16* __restrict__ kb,
    const bf16* __restrict__ vT, bf16* __restrict__ attnb)
{
    const int qt = blockIdx.x, h = blockIdx.y, b = blockIdx.z;
    const int tid = threadIdx.x, lane = tid & 63, wave = tid >> 6;
    const int qd = lane >> 4, lr = lane & 15;
    const int q0 = qt*64 + wave*16;

    __shared__ bf16 Ks[2][64*64];
    __shared__ bf16 Vs[2][64*64];
    __shared__ bf16 Pl[4][16][72];

    bf16x8 aq0, aq1;
    {
        const bf16* qrow = qb + ((size_t)(b*1024 + q0 + lr))*512 + h*64;
        aq0 = *(const bf16x8*)(qrow + qd*8);
        aq1 = *(const bf16x8*)(qrow + 32 + qd*8);
    }

    const int srow = (tid >> 3) & 7;
    const int sgr  = ((tid&7) ^ srow) * 8;
    const bf16* kgp = kb + ((size_t)(b*1024 + wave*8 + srow))*512 + h*64 + sgr;
    const bf16* vgp = vT + ((size_t)((b*8 + h)*64 + wave*8 + srow))*1024 + sgr;
    const int woff = wave*512;

    // preload tile 0 into buffer 0
    async16p(kgp,                    &Ks[0][woff]);
    async16p(kgp + (size_t)32*512,   &Ks[0][woff + 2048]);
    async16p(vgp,                    &Vs[0][woff]);
    async16p(vgp + (size_t)32*1024,  &Vs[0][woff + 2048]);

    f32x4 acc[4];
    #pragma unroll
    for (int i=0;i<4;i++) acc[i] = (f32x4){0,0,0,0};
    float l[4] = {0.f,0.f,0.f,0.f};

    for (int t=0; t<16; ++t) {
        const int cur = t & 1;
        __syncthreads();   // tile-t loads complete; buf[1-cur] readers done
        if (t < 15) {      // issue t+1 into the other buffer; overlaps compute
            const int nb = 1 - cur;
            const size_t kk = (size_t)(t+1)*64;
            async16p(kgp + kk*512,             &Ks[nb][woff]);
            async16p(kgp + (kk+32)*512,        &Ks[nb][woff + 2048]);
            async16p(vgp + kk,                 &Vs[nb][woff]);
            async16p(vgp + (size_t)32*1024+kk, &Vs[nb][woff + 2048]);
        }
        const bf16* kc = &Ks[cur][0];
        const bf16* vc = &Vs[cur][0];

        f32x4 s[4];
        #pragma unroll
        for (int ni=0;ni<4;ni++) s[ni] = (f32x4){0,0,0,0};
        #pragma unroll
        for (int ni=0;ni<4;ni++) {
            int row = ni*16 + lr;
            bf16x8 b0 = *(bf16x8*)(kc + row*64 + (((qd  )^(lr&7))*8));
            bf16x8 b1 = *(bf16x8*)(kc + row*64 + (((qd+4)^(lr&7))*8));
            s[ni] = MFMA16(aq0, b0, s[ni]);
            s[ni] = MFMA16(aq1, b1, s[ni]);
        }
        #pragma unroll
        for (int ni=0;ni<4;ni++)
          #pragma unroll
          for (int r=0;r<4;r++) {
            float pv = __expf(s[ni][r] * ATT_SCALE);
            s[ni][r] = pv;
            l[r] += pv;
          }
        #pragma unroll
        for (int ni=0;ni<4;ni++)
          #pragma unroll
          for (int r=0;r<4;r++)
            Pl[wave][qd*4+r][ni*16+lr] = (bf16)s[ni][r];
        bf16x8 ap0 = *(bf16x8*)(&Pl[wave][lr][qd*8]);
        bf16x8 ap1 = *(bf16x8*)(&Pl[wave][lr][32+qd*8]);
        #pragma unroll
        for (int ni=0;ni<4;ni++) {
            int row = ni*16 + lr;
            bf16x8 v0 = *(bf16x8*)(vc + row*64 + (((qd  )^(lr&7))*8));
            bf16x8 v1 = *(bf16x8*)(vc + row*64 + (((qd+4)^(lr&7))*8));
            acc[ni] = MFMA16(ap0, v0, acc[ni]);
            acc[ni] = MFMA16(ap1, v1, acc[ni]);
        }
    }

    #pragma unroll
    for (int off=1; off<16; off<<=1)
      #pragma unroll
      for (int r=0;r<4;r++) l[r] += __shfl_xor(l[r], off);

    float inv[4];
    #pragma unroll
    for (int r=0;r<4;r++) inv[r] = 1.f / l[r];
    #pragma unroll
    for (int ni=0;ni<4;ni++)
      #pragma unroll
      for (int r=0;r<4;r++)
        Pl[wave][qd*4+r][ni*16+lr] = (bf16)(acc[ni][r] * inv[r]);
    bf16x8 oA = *(bf16x8*)(&Pl[wave][lr][qd*8]);
    bf16x8 oB = *(bf16x8*)(&Pl[wave][lr][32+qd*8]);
    bf16* dst = attnb + ((size_t)(b*1024 + q0 + lr))*512 + h*64;
    *(bf16x8*)(dst + qd*8)      = oA;
    *(bf16x8*)(dst + 32 + qd*8) = oB;
}

// ---------------- ln0: Obf = LN(q + attn)  (bf16 in/out) -------------------
__global__ __launch_bounds__(256) void ln0_kernel(
    const bf16* __restrict__ qbb, const bf16* __restrict__ attnb,
    bf16* __restrict__ Obf)
{
    const int wave = threadIdx.x >> 6, lane = threadIdx.x & 63;
    const int row = blockIdx.x*4 + wave;
    const size_t base = (size_t)row*512 + lane*8;
    bf16x8 qv = *(const bf16x8*)(qbb + base);
    bf16x8 av = *(const bf16x8*)(attnb + base);
    float x[8];
    #pragma unroll
    for (int i=0;i<8;i++) x[i] = (float)qv[i] + (float)av[i];
    float s1 = 0.f, s2 = 0.f;
    #pragma unroll
    for (int i=0;i<8;i++){ s1 += x[i]; s2 += x[i]*x[i]; }
    #pragma unroll
    for (int off=1; off<64; off<<=1) { s1 += __shfl_xor(s1, off); s2 += __shfl_xor(s2, off); }
    float mu  = s1 * (1.f/512.f);
    float var = s2 * (1.f/512.f) - mu*mu;
    float rstd = rsqrtf(var + 1e-5f);
    bf16x8 ob;
    #pragma unroll
    for (int i=0;i<8;i++) ob[i] = (bf16)((x[i]-mu)*rstd);
    *(bf16x8*)(Obf + base) = ob;
}

// ------- gemm_o: G = Obf@WoT + bo; xb = Obf + gelu(G)  (bf16 out) ----------
__global__ __launch_bounds__(256, 3) void gemm_o_kernel(
    const bf16* __restrict__ Obf, const bf16* __restrict__ WoT,
    const float* __restrict__ bo, bf16* __restrict__ xb)
{
    __shared__ bf16 As[128*32];
    __shared__ bf16 Bs[128*32];
    const int m0 = blockIdx.x * 128, n0 = blockIdx.y * 128;
    const int tid = threadIdx.x;
    const int lane = tid & 63, wave = tid >> 6;
    const int qd = lane >> 4, lr = lane & 15;
    const int wm = (wave & 1) * 64, wn = (wave >> 1) * 64;

    const int gr = ((tid&3)^((tid>>2)&3))*8;
    const bf16* gA = Obf + (size_t)(m0 + (tid>>2))*512 + gr;
    const bf16* gB = WoT + (size_t)(n0 + (tid>>2))*512 + gr;
    bf16* lA = As + wave*512;
    bf16* lB = Bs + wave*512;

    f32x4 acc[4][4];
    #pragma unroll
    for (int i=0;i<4;i++)
      #pragma unroll
      for (int j=0;j<4;j++) acc[i][j] = (f32x4){0,0,0,0};

    for (int k0 = 0; k0 < 512; k0 += 32) {
        __syncthreads();
        async16p(gA + k0,          lA);
        async16p(gA + k0 + 64*512, lA + 2048);
        async16p(gB + k0,          lB);
        async16p(gB + k0 + 64*512, lB + 2048);
        __syncthreads();
        bf16x8 af[4], bfr[4];
        #pragma unroll
        for (int mi=0;mi<4;mi++) af[mi]  = *(bf16x8*)(As + (wm+mi*16+lr)*32 + ((qd^(lr&3))*8));
        #pragma unroll
        for (int ni=0;ni<4;ni++) bfr[ni] = *(bf16x8*)(Bs + (wn+ni*16+lr)*32 + ((qd^(lr&3))*8));
        #pragma unroll
        for (int mi=0;mi<4;mi++)
          #pragma unroll
          for (int ni=0;ni<4;ni++)
            acc[mi][ni] = MFMA16(af[mi], bfr[ni], acc[mi][ni]);
    }

    #pragma unroll
    for (int ni=0;ni<4;ni++) {
        int n = n0 + wn + ni*16 + lr;
        float bv = bo[n];
        #pragma unroll
        for (int mi=0;mi<4;mi++) {
            int mb = m0 + wm + mi*16 + qd*4;
            #pragma unroll
            for (int r=0;r<4;r++) {
                float g = acc[mi][ni][r] + bv;
                float gelu = 0.5f * g * (1.f + erff(g * 0.70710678118654752f));
                size_t idx = (size_t)(mb+r)*512 + n;
                xb[idx] = (bf16)((float)Obf[idx] + gelu);
            }
        }
    }
}

// ---------------- ln1: out = LN(xb) ----------------
__global__ __launch_bounds__(256) void ln1_kernel(
    const bf16* __restrict__ xb, float* __restrict__ out)
{
    const int wave = threadIdx.x >> 6, lane = threadIdx.x & 63;
    const int row = blockIdx.x*4 + wave;
    const size_t base = (size_t)row*512 + lane*8;
    bf16x8 xv = *(const bf16x8*)(xb + base);
    float x[8];
    #pragma unroll
    for (int i=0;i<8;i++) x[i] = (float)xv[i];
    float s1 = 0.f, s2 = 0.f;
    #pragma unroll
    for (int i=0;i<8;i++){ s1 += x[i]; s2 += x[i]*x[i]; }
    #pragma unroll
    for (int off=1; off<64; off<<=1) { s1 += __shfl_xor(s1, off); s2 += __shfl_xor(s2, off); }
    float mu  = s1 * (1.f/512.f);
    float var = s2 * (1.f/512.f) - mu*mu;
    float rstd = rsqrtf(var + 1e-5f);
    float4 o0 = {(x[0]-mu)*rstd,(x[1]-mu)*rstd,(x[2]-mu)*rstd,(x[3]-mu)*rstd};
    float4 o1 = {(x[4]-mu)*rstd,(x[5]-mu)*rstd,(x[6]-mu)*rstd,(x[7]-mu)*rstd};
    *(float4*)(out + base)     = o0;
    *(float4*)(out + base + 4) = o1;
}

extern "C" void kernel_launch(void* const* d_in, const int* in_sizes, int n_in,
                              void* d_out, int out_size, void* d_ws, size_t ws_size,
                              hipStream_t stream)
{
    (void)in_sizes; (void)n_in; (void)out_size; (void)ws_size;
    const float* Q  = (const float*)d_in[0];
    const float* K  = (const float*)d_in[1];
    const float* Wq = (const float*)d_in[2];
    const float* bq = (const float*)d_in[3];
    const float* Wk = (const float*)d_in[4];
    const float* bk = (const float*)d_in[5];
    const float* Wv = (const float*)d_in[6];
    const float* bv = (const float*)d_in[7];
    const float* Wo = (const float*)d_in[8];
    const float* bo = (const float*)d_in[9];
    float* out = (float*)d_out;

    const size_t nTok = (size_t)16*1024*512;
    char* p = (char*)d_ws;
    auto alloc = [&](size_t bytes)->char* {
        char* r = p; p += (bytes + 255) & ~(size_t)255; return r;
    };
    bf16* WqT   = (bf16*)alloc(512*512*2);
    bf16* WkT   = (bf16*)alloc(512*512*2);
    bf16* WvT   = (bf16*)alloc(512*512*2);
    bf16* WoT   = (bf16*)alloc(512*512*2);
    bf16* qbb   = (bf16*)alloc(nTok*2);
    bf16* kbb   = (bf16*)alloc(nTok*2);
    bf16* vT    = (bf16*)alloc(nTok*2);
    bf16* attnb = (bf16*)alloc(nTok*2);
    bf16* Obf   = (bf16*)alloc(nTok*2);
    bf16* xb    = (bf16*)alloc(nTok*2);

    prep_w_kernel<<<1024, 256, 0, stream>>>(Wq, Wk, Wv, Wo, WqT, WkT, WvT, WoT);
    gemm_qkv_kernel<<<dim3(128,4,3), 256, 0, stream>>>(Q, K, WqT, WkT, WvT,
                                                       bq, bk, bv, qbb, kbb, vT);
    attn_kernel<<<dim3(16,8,16), 256, 0, stream>>>(qbb, kbb, vT, attnb);
    ln0_kernel<<<4096, 256, 0, stream>>>(qbb, attnb, Obf);
    gemm_o_kernel<<<dim3(128,4), 256, 0, stream>>>(Obf, WoT, bo, xb);
    ln1_kernel<<<4096, 256, 0, stream>>>(xb, out);
}